// Round 2
// baseline (1355.743 us; speedup 1.0000x reference)
//
#include <hip/hip_runtime.h>
#include <hip/hip_cooperative_groups.h>

// GlobalSLC: out = out_s + out_d
//   static : y1 = ws@x; y2 = 2ws@y1 - x; y3 = 2ws@y2 - y1
//   dynamic: collapses to 32x32 algebra (G = x^T x, W = G wp, H1 = W G, H2 = 2 W H1 - G)
//   out = x@(2ts0-td2) + xp@(G td1 + 2 H1 td2 + (2H2-G) td3) + y1@ts1 + y2@ts2 + y3@ts3
//
// R7: single persistent cooperative kernel. ws is staged bf16 into REGISTERS
// (128 VGPR/thread, 1024 blocks x 256 thr = 128 MB chip-wide) once; all three
// Chebyshev passes run from registers with grid syncs. Eliminates the 128 MB
// wsb write + 256 MB of wsb re-reads and all inter-kernel launch/tail overhead.
// Vb/Ypart are multi-buffered (write-once per buffer) so coherence needs only
// the grid-sync fences. Fallback to the R6 multi-kernel path if cooperative
// launch is unavailable.

namespace cg = cooperative_groups;

typedef __attribute__((ext_vector_type(8))) short short8;
typedef __attribute__((ext_vector_type(4))) float floatx4;

constexpr int NSPLIT = 8;       // split-K; 1024 cols per split

__device__ inline unsigned short f2bf(float f) {
    union { float f; unsigned u; } v; v.f = f;
    unsigned r = v.u + 0x7FFFu + ((v.u >> 16) & 1u);   // RNE
    return (unsigned short)(r >> 16);
}

__device__ inline floatx4 ntload4(const float* p) {
    return __builtin_nontemporal_load((const floatx4*)p);
}

struct __align__(16) SMem {
    union {
        unsigned short sbuf[4][16 * 256];                                   // 32 KB staging
        struct { float swp[1024]; unsigned short st[32][136]; } prep;       // 12.5 KB
        struct { float G[1024], W[1024], H1[1024], H2[1024]; } coef;        // 16 KB
        unsigned short st16[32][48];                                        // 3 KB
        float fin[5][1024];                                                 // 20 KB
    };
};

// ================= persistent cooperative kernel =================
__global__ __launch_bounds__(256, 4) void k_all(
    const float* __restrict__ x, const float* __restrict__ ws,
    const float* __restrict__ wp, const float* __restrict__ ts,
    const float* __restrict__ td, float* __restrict__ out,
    float* __restrict__ xp, float* __restrict__ y1,
    float* __restrict__ y2, float* __restrict__ y3,
    unsigned short* __restrict__ Vb0, unsigned short* __restrict__ Vb1,
    unsigned short* __restrict__ Vb2, float* __restrict__ Yp,
    float* __restrict__ Gpart, float* __restrict__ Cx, float* __restrict__ Cxp)
{
    cg::grid_group grid = cg::this_grid();
    __shared__ SMem sm;
    const int t = threadIdx.x;
    const int lane = t & 63, wv = t >> 6, l15 = lane & 15, l4 = lane >> 4;
    const int bid = blockIdx.x;
    const int bx = bid >> 3, by = bid & 7;
    const int k0 = by * 1024, kc0 = by * 32;
    const int rowbase = bx * 64 + wv * 16;

    // ---- prep (blocks 0..63, 128 rows each): xp = x@wp, Gram partials, Vb0 ----
    if (bid < 64) {
        const int n0 = bid * 128;
        for (int i = t; i < 1024; i += 256) sm.prep.swp[i] = wp[i];
        __syncthreads();
        if (t < 128) {
            const float* xr = x + (size_t)(n0 + t) * 32;
            float row[32];
#pragma unroll
            for (int a = 0; a < 32; ++a) row[a] = xr[a];
            float* xpr = xp + (size_t)(n0 + t) * 32;
#pragma unroll
            for (int c = 0; c < 32; ++c) {
                float s = 0.f;
#pragma unroll
                for (int a = 0; a < 32; ++a) s += row[a] * sm.prep.swp[a * 32 + c];
                xpr[c] = s;
                sm.prep.st[c][t] = f2bf(row[c]);
            }
        }
        {
            const int a = t >> 3, b4 = 4 * (t & 7);
            float g0 = 0.f, g1 = 0.f, g2 = 0.f, g3 = 0.f;
            for (int i = 0; i < 128; ++i) {
                float va = x[(size_t)(n0 + i) * 32 + a];
                floatx4 vb = *(const floatx4*)&x[(size_t)(n0 + i) * 32 + b4];
                g0 += va * vb.x; g1 += va * vb.y; g2 += va * vb.z; g3 += va * vb.w;
            }
            floatx4 g = {g0, g1, g2, g3};
            *(floatx4*)&Gpart[(size_t)bid * 1024 + (size_t)(a * 32 + b4)] = g;
        }
        __syncthreads();
        short8* Vb8 = (short8*)Vb0;
#pragma unroll
        for (int q = 0; q < 2; ++q) {
            int idx = wv * 2 + q;
            int c8 = idx >> 1, h = idx & 1;
            short8 v = *(const short8*)&sm.prep.st[h * 16 + l15][c8 * 32 + l4 * 8];
            Vb8[((size_t)(n0 / 32 + c8) * 2 + h) * 64 + lane] = v;
        }
        __syncthreads();   // smem reused as sbuf below
    }

    // ---- stage A: ws row-tile (64 x 1024 fp32) -> wreg[32] bf16 fragments ----
    short8 wreg[32];
    {
        unsigned short* mybuf = sm.sbuf[wv];
        const int wchunk = lane >> 1, whalf = lane & 1;
#pragma unroll
        for (int s = 0; s < 4; ++s) {
            const int ks = k0 + s * 256;
#pragma unroll
            for (int r = 0; r < 16; ++r) {
                floatx4 f = ntload4(ws + (size_t)(rowbase + r) * 8192 + ks + lane * 4);
                ushort4 h;
                h.x = f2bf(f.x); h.y = f2bf(f.y); h.z = f2bf(f.z); h.w = f2bf(f.w);
                *(ushort4*)(mybuf + r * 256 + ((wchunk ^ r) * 8 + whalf * 4)) = h;
            }
#pragma unroll
            for (int kk = 0; kk < 8; ++kk)
                wreg[s * 8 + kk] = *(short8*)(mybuf + l15 * 256 + (((kk * 4 + l4) ^ l15) * 8));
        }
    }
    grid.sync();

#define DO_PASS(VBSRC, YDST)                                                          \
    {                                                                                 \
        const short8* Vb8_ = (const short8*)(VBSRC);                                  \
        floatx4 acc0 = {0.f, 0.f, 0.f, 0.f};                                          \
        floatx4 acc1 = {0.f, 0.f, 0.f, 0.f};                                          \
        _Pragma("unroll")                                                             \
        for (int c = 0; c < 32; ++c) {                                                \
            short8 b0 = Vb8_[((size_t)(kc0 + c) * 2 + 0) * 64 + lane];                \
            short8 b1 = Vb8_[((size_t)(kc0 + c) * 2 + 1) * 64 + lane];                \
            acc0 = __builtin_amdgcn_mfma_f32_16x16x32_bf16(wreg[c], b0, acc0, 0, 0, 0); \
            acc1 = __builtin_amdgcn_mfma_f32_16x16x32_bf16(wreg[c], b1, acc1, 0, 0, 0); \
        }                                                                             \
        float* yp_ = (YDST) + (size_t)by * 262144;                                    \
        const int row0_ = bx * 64 + wv * 16 + l4 * 4;                                 \
        _Pragma("unroll")                                                             \
        for (int r = 0; r < 4; ++r) {                                                 \
            yp_[(size_t)(row0_ + r) * 32 + l15] = acc0[r];                            \
            yp_[(size_t)(row0_ + r) * 32 + 16 + l15] = acc1[r];                       \
        }                                                                             \
    }

#define DO_TRANS(YSRC, PREV, ALPHA, BETA, YOUT, VBE, EMIT)                            \
    if (bid >= 1 && bid <= 256) {                                                     \
        const int kc_ = bid - 1;                                                      \
        const int row_ = t >> 3, c4_ = (t & 7) * 4;                                   \
        const size_t base_ = ((size_t)kc_ * 32 + row_) * 32 + c4_;                    \
        floatx4 racc = {0.f, 0.f, 0.f, 0.f};                                          \
        _Pragma("unroll")                                                             \
        for (int p = 0; p < NSPLIT; ++p) {                                            \
            floatx4 v_ = ntload4((YSRC) + (size_t)p * 262144 + base_);                \
            racc.x += v_.x; racc.y += v_.y; racc.z += v_.z; racc.w += v_.w;           \
        }                                                                             \
        floatx4 pv = *(const floatx4*)((PREV) + base_);                               \
        floatx4 v;                                                                    \
        v.x = (ALPHA) * racc.x + (BETA) * pv.x;                                       \
        v.y = (ALPHA) * racc.y + (BETA) * pv.y;                                       \
        v.z = (ALPHA) * racc.z + (BETA) * pv.z;                                       \
        v.w = (ALPHA) * racc.w + (BETA) * pv.w;                                       \
        *(floatx4*)((YOUT) + base_) = v;                                              \
        if (EMIT) {                                                                   \
            sm.st16[c4_ + 0][row_] = f2bf(v.x);                                       \
            sm.st16[c4_ + 1][row_] = f2bf(v.y);                                       \
            sm.st16[c4_ + 2][row_] = f2bf(v.z);                                       \
            sm.st16[c4_ + 3][row_] = f2bf(v.w);                                       \
            __syncthreads();                                                          \
            if (wv < 2) {                                                             \
                short8 vv = *(const short8*)&sm.st16[wv * 16 + l15][l4 * 8];          \
                ((short8*)(VBE))[((size_t)kc_ * 2 + wv) * 64 + lane] = vv;            \
            }                                                                         \
        }                                                                             \
    }

    // ---- pass 1: y1 = ws @ x ----
    DO_PASS(Vb0, Yp)
    grid.sync();
    DO_TRANS(Yp, x, 1.f, 0.f, y1, Vb1, 1)
    if (bid == 0) {
        // 32x32 coefficient algebra (runs in the trans-1 slot)
#pragma unroll
        for (int j = 0; j < 4; ++j) {
            int e = t + j * 256;
            float g = 0.f;
            for (int p = 0; p < 64; ++p) g += Gpart[p * 1024 + e];
            sm.coef.G[e] = g;
        }
        __syncthreads();
#pragma unroll
        for (int j = 0; j < 4; ++j) {
            int e = t + j * 256, a = e >> 5, b = e & 31;
            float s = 0.f;
            for (int c = 0; c < 32; ++c) s += sm.coef.G[a * 32 + c] * wp[c * 32 + b];
            sm.coef.W[e] = s;
        }
        __syncthreads();
#pragma unroll
        for (int j = 0; j < 4; ++j) {
            int e = t + j * 256, a = e >> 5, b = e & 31;
            float s = 0.f;
            for (int c = 0; c < 32; ++c) s += sm.coef.W[a * 32 + c] * sm.coef.G[c * 32 + b];
            sm.coef.H1[e] = s;
        }
        __syncthreads();
#pragma unroll
        for (int j = 0; j < 4; ++j) {
            int e = t + j * 256, a = e >> 5, b = e & 31;
            float s = 0.f;
            for (int c = 0; c < 32; ++c) s += sm.coef.W[a * 32 + c] * sm.coef.H1[c * 32 + b];
            sm.coef.H2[e] = 2.f * s - sm.coef.G[e];
        }
        __syncthreads();
#pragma unroll
        for (int j = 0; j < 4; ++j) {
            int e = t + j * 256, a = e >> 5, b = e & 31;
            float s = 0.f;
            for (int c = 0; c < 32; ++c)
                s += sm.coef.G[a * 32 + c] * td[1024 + c * 32 + b]
                   + 2.f * sm.coef.H1[a * 32 + c] * td[2048 + c * 32 + b]
                   + (2.f * sm.coef.H2[a * 32 + c] - sm.coef.G[a * 32 + c]) * td[3072 + c * 32 + b];
            Cxp[e] = s;
            Cx[e] = 2.f * ts[e] - td[2048 + e];
        }
    }
    grid.sync();
    // ---- pass 2: y2 = 2 ws @ y1 - x ----
    DO_PASS(Vb1, Yp + 2097152)
    grid.sync();
    DO_TRANS(Yp + 2097152, x, 2.f, -1.f, y2, Vb2, 1)
    grid.sync();
    // ---- pass 3: y3 = 2 ws @ y2 - y1 ----
    DO_PASS(Vb2, Yp + 4194304)
    grid.sync();
    DO_TRANS(Yp + 4194304, y1, 2.f, -1.f, y3, Vb2, 0)
    grid.sync();

    // ---- final: out = x@Cx + xp@Cxp + y1@ts1 + y2@ts2 + y3@ts3 (8 rows/block) ----
    for (int i = t; i < 1024; i += 256) {
        sm.fin[0][i] = Cx[i]; sm.fin[1][i] = Cxp[i];
        sm.fin[2][i] = ts[1024 + i]; sm.fin[3][i] = ts[2048 + i]; sm.fin[4][i] = ts[3072 + i];
    }
    __syncthreads();
    {
        const int n = bid * 8 + (t >> 5), c = t & 31;
        const float* xr  = x  + (size_t)n * 32;
        const float* xpr = xp + (size_t)n * 32;
        const float* y1r = y1 + (size_t)n * 32;
        const float* y2r = y2 + (size_t)n * 32;
        const float* y3r = y3 + (size_t)n * 32;
        float s = 0.f;
#pragma unroll
        for (int a = 0; a < 32; ++a) {
            s += xr[a]  * sm.fin[0][a * 32 + c]
               + xpr[a] * sm.fin[1][a * 32 + c]
               + y1r[a] * sm.fin[2][a * 32 + c]
               + y2r[a] * sm.fin[3][a * 32 + c]
               + y3r[a] * sm.fin[4][a * 32 + c];
        }
        out[(size_t)n * 32 + c] = s;
    }
#undef DO_PASS
#undef DO_TRANS
}

// ================= fallback: R6 multi-kernel path =================
__global__ __launch_bounds__(256) void k_prep(const float* __restrict__ x,
                                              const float* __restrict__ wp,
                                              float* __restrict__ xp,
                                              float* __restrict__ Gpart,
                                              unsigned short* __restrict__ Vb) {
    __shared__ float sx[8192];
    __shared__ float swp[1024];
    __shared__ unsigned short st[32][264];
    const int t = threadIdx.x;
    const int n0 = blockIdx.x * 256;
    const floatx4* x4 = (const floatx4*)(x + (size_t)n0 * 32);
    floatx4* sx4 = (floatx4*)sx;
#pragma unroll
    for (int i = 0; i < 8; ++i) sx4[i * 256 + t] = x4[i * 256 + t];
    for (int i = t; i < 1024; i += 256) swp[i] = wp[i];
    __syncthreads();
    float row[32];
#pragma unroll
    for (int a = 0; a < 32; ++a) row[a] = sx[t * 32 + a];
    float* xpr = xp + (size_t)(n0 + t) * 32;
#pragma unroll
    for (int c = 0; c < 32; ++c) {
        float s = 0.f;
#pragma unroll
        for (int a = 0; a < 32; ++a) s += row[a] * swp[a * 32 + c];
        xpr[c] = s;
        st[c][t] = f2bf(row[c]);
    }
    const int a = t >> 3;
    const int b = 4 * (t & 7);
    float g0 = 0.f, g1 = 0.f, g2 = 0.f, g3 = 0.f;
    for (int i = 0; i < 256; ++i) {
        float va = sx[i * 32 + a];
        floatx4 vb = *(floatx4*)&sx[i * 32 + b];
        g0 += va * vb.x; g1 += va * vb.y; g2 += va * vb.z; g3 += va * vb.w;
    }
    floatx4 g = {g0, g1, g2, g3};
    *(floatx4*)&Gpart[(size_t)blockIdx.x * 1024 + (size_t)(a * 32 + b)] = g;
    __syncthreads();
    const int lane = t & 63, wv = t >> 6;
    const int l15 = lane & 15, l4 = lane >> 4;
    short8* Vb8 = (short8*)Vb;
#pragma unroll
    for (int q = 0; q < 4; ++q) {
        int idx = wv * 4 + q;
        int c8 = idx >> 1, h = idx & 1;
        short8 v = *(const short8*)&st[h * 16 + l15][c8 * 32 + l4 * 8];
        Vb8[((size_t)(n0 / 32 + c8) * 2 + h) * 64 + lane] = v;
    }
}

__global__ void k_coef(const float* __restrict__ Gpart, const float* __restrict__ wp,
                       const float* __restrict__ ts, const float* __restrict__ td,
                       float* __restrict__ Cx, float* __restrict__ Cxp) {
    __shared__ float G[1024], W[1024], H1[1024], H2[1024];
    __shared__ float swp[1024], td1[1024], td2[1024], td3[1024], ts0[1024];
    int t = threadIdx.x;
    int a = t >> 5, b = t & 31;
    float gs = 0.f;
    for (int p = 0; p < 32; ++p) gs += Gpart[p * 1024 + t];
    G[t] = gs; swp[t] = wp[t]; ts0[t] = ts[t];
    td1[t] = td[1024 + t]; td2[t] = td[2048 + t]; td3[t] = td[3072 + t];
    __syncthreads();
    float s = 0.f;
    for (int c = 0; c < 32; ++c) s += G[a * 32 + c] * swp[c * 32 + b];
    W[t] = s; __syncthreads();
    s = 0.f;
    for (int c = 0; c < 32; ++c) s += W[a * 32 + c] * G[c * 32 + b];
    H1[t] = s; __syncthreads();
    s = 0.f;
    for (int c = 0; c < 32; ++c) s += W[a * 32 + c] * H1[c * 32 + b];
    H2[t] = 2.f * s - G[t]; __syncthreads();
    s = 0.f;
    for (int c = 0; c < 32; ++c)
        s += G[a * 32 + c] * td1[c * 32 + b]
           + 2.f * H1[a * 32 + c] * td2[c * 32 + b]
           + (2.f * H2[a * 32 + c] - G[a * 32 + c]) * td3[c * 32 + b];
    Cxp[t] = s;
    Cx[t] = 2.f * ts0[t] - td2[t];
}

__global__ __launch_bounds__(256) void k_gemm1(const float* __restrict__ A,
                                               unsigned short* __restrict__ wsb,
                                               const unsigned short* __restrict__ Vb,
                                               float* __restrict__ Ypart) {
    __shared__ unsigned short sbuf[4][16 * 256];
    const int t = threadIdx.x;
    const int lane = t & 63;
    const int wv = t >> 6;
    const int l15 = lane & 15;
    const int l4 = lane >> 4;
    const int bx = blockIdx.x, by = blockIdx.y;
    const int k0 = by * 1024;
    const int kc0 = by * 32;
    const int rowbase = bx * 64 + wv * 16;
    unsigned short* wout =
        wsb + (((size_t)(bx * NSPLIT + by) * 8192) + (size_t)wv * 64 + lane) * 8;
    const short8* Vb8 = (const short8*)Vb;
    unsigned short* mybuf = sbuf[wv];
    const int wchunk = lane >> 1, whalf = lane & 1;
    floatx4 acc0 = {0.f, 0.f, 0.f, 0.f};
    floatx4 acc1 = {0.f, 0.f, 0.f, 0.f};
    for (int s = 0; s < 4; ++s) {
        const int ks = k0 + s * 256;
#pragma unroll
        for (int r = 0; r < 16; ++r) {
            floatx4 f = ntload4(A + (size_t)(rowbase + r) * 8192 + ks + lane * 4);
            ushort4 h;
            h.x = f2bf(f.x); h.y = f2bf(f.y); h.z = f2bf(f.z); h.w = f2bf(f.w);
            *(ushort4*)(mybuf + r * 256 + ((wchunk ^ r) * 8 + whalf * 4)) = h;
        }
#pragma unroll 4
        for (int kk = 0; kk < 8; ++kk) {
            short8 av = *(short8*)(mybuf + l15 * 256 + (((kk * 4 + l4) ^ l15) * 8));
            const int kc = kc0 + s * 8 + kk;
            short8 b0 = Vb8[((size_t)kc * 2 + 0) * 64 + lane];
            short8 b1 = Vb8[((size_t)kc * 2 + 1) * 64 + lane];
            *(short8*)(wout + (size_t)(s * 8 + kk) * 2048) = av;
            acc0 = __builtin_amdgcn_mfma_f32_16x16x32_bf16(av, b0, acc0, 0, 0, 0);
            acc1 = __builtin_amdgcn_mfma_f32_16x16x32_bf16(av, b1, acc1, 0, 0, 0);
        }
    }
    float* yp = Ypart + (size_t)by * 262144;
    const int row0 = bx * 64 + wv * 16 + l4 * 4;
#pragma unroll
    for (int r = 0; r < 4; ++r) {
        yp[(size_t)(row0 + r) * 32 + l15] = acc0[r];
        yp[(size_t)(row0 + r) * 32 + 16 + l15] = acc1[r];
    }
}

__global__ __launch_bounds__(256) void k_gemm2(const unsigned short* __restrict__ wsb,
                                               const unsigned short* __restrict__ Vb,
                                               float* __restrict__ Ypart) {
    const int t = threadIdx.x;
    const int lane = t & 63;
    const int wv = t >> 6;
    const int l15 = lane & 15;
    const int l4 = lane >> 4;
    const int bx = blockIdx.x, by = blockIdx.y;
    const int kc0 = by * 32;
    const short8* win = (const short8*)wsb
        + ((size_t)(bx * NSPLIT + by) * 8192) + (size_t)wv * 64 + lane;
    const short8* Vb8 = (const short8*)Vb;
    floatx4 acc0 = {0.f, 0.f, 0.f, 0.f};
    floatx4 acc1 = {0.f, 0.f, 0.f, 0.f};
#pragma unroll 8
    for (int c = 0; c < 32; ++c) {
        short8 av = win[(size_t)c * 256];
        short8 b0 = Vb8[((size_t)(kc0 + c) * 2 + 0) * 64 + lane];
        short8 b1 = Vb8[((size_t)(kc0 + c) * 2 + 1) * 64 + lane];
        acc0 = __builtin_amdgcn_mfma_f32_16x16x32_bf16(av, b0, acc0, 0, 0, 0);
        acc1 = __builtin_amdgcn_mfma_f32_16x16x32_bf16(av, b1, acc1, 0, 0, 0);
    }
    float* yp = Ypart + (size_t)by * 262144;
    const int row0 = bx * 64 + wv * 16 + l4 * 4;
#pragma unroll
    for (int r = 0; r < 4; ++r) {
        yp[(size_t)(row0 + r) * 32 + l15] = acc0[r];
        yp[(size_t)(row0 + r) * 32 + 16 + l15] = acc1[r];
    }
}

__global__ __launch_bounds__(256) void k_trans(const float* __restrict__ Ypart,
                                               const float* __restrict__ prev,
                                               float alpha, float beta,
                                               float* __restrict__ y,
                                               unsigned short* __restrict__ Vb) {
    __shared__ unsigned short st[32][264];
    const int t = threadIdx.x;
    const int n0 = blockIdx.x * 256;
    const size_t base4 = (size_t)n0 * 8;
    floatx4 r[8];
#pragma unroll
    for (int j = 0; j < 8; ++j) r[j] = {0.f, 0.f, 0.f, 0.f};
    for (int p = 0; p < NSPLIT; ++p) {
        const float* P = Ypart + (size_t)p * 262144;
#pragma unroll
        for (int j = 0; j < 8; ++j)
            r[j] += ntload4(P + (base4 + j * 256 + t) * 4);
    }
    const floatx4* prev4 = (const floatx4*)prev;
    floatx4* y4 = (floatx4*)y;
#pragma unroll
    for (int j = 0; j < 8; ++j) {
        floatx4 pv = prev4[base4 + j * 256 + t];
        floatx4 v;
        v.x = alpha * r[j].x + beta * pv.x;
        v.y = alpha * r[j].y + beta * pv.y;
        v.z = alpha * r[j].z + beta * pv.z;
        v.w = alpha * r[j].w + beta * pv.w;
        y4[base4 + j * 256 + t] = v;
        int q = j * 256 + t;
        int lr = q >> 3;
        int c4 = (q & 7) * 4;
        st[c4 + 0][lr] = f2bf(v.x);
        st[c4 + 1][lr] = f2bf(v.y);
        st[c4 + 2][lr] = f2bf(v.z);
        st[c4 + 3][lr] = f2bf(v.w);
    }
    __syncthreads();
    const int lane = t & 63, wv = t >> 6;
    const int l15 = lane & 15, l4 = lane >> 4;
    short8* Vb8 = (short8*)Vb;
#pragma unroll
    for (int q = 0; q < 4; ++q) {
        int idx = wv * 4 + q;
        int c8 = idx >> 1, h = idx & 1;
        short8 v = *(const short8*)&st[h * 16 + l15][c8 * 32 + l4 * 8];
        Vb8[((size_t)(n0 / 32 + c8) * 2 + h) * 64 + lane] = v;
    }
}

__global__ void k_final(const float* __restrict__ x, const float* __restrict__ xp,
                        const float* __restrict__ y1, const float* __restrict__ y2,
                        const float* __restrict__ y3, const float* __restrict__ Cx,
                        const float* __restrict__ Cxp, const float* __restrict__ ts,
                        float* __restrict__ out) {
    __shared__ float m0[1024], m1[1024], m2[1024], m3[1024], m4[1024];
    int t = threadIdx.x;
    for (int i = t; i < 1024; i += 256) {
        m0[i] = Cx[i]; m1[i] = Cxp[i];
        m2[i] = ts[1024 + i]; m3[i] = ts[2048 + i]; m4[i] = ts[3072 + i];
    }
    __syncthreads();
    int g = blockIdx.x * 256 + t;
    int n = g >> 5, c = g & 31;
    const float* xr  = x  + (size_t)n * 32;
    const float* xpr = xp + (size_t)n * 32;
    const float* y1r = y1 + (size_t)n * 32;
    const float* y2r = y2 + (size_t)n * 32;
    const float* y3r = y3 + (size_t)n * 32;
    float s = 0.f;
#pragma unroll
    for (int a = 0; a < 32; ++a) {
        s += xr[a]  * m0[a * 32 + c]
           + xpr[a] * m1[a * 32 + c]
           + y1r[a] * m2[a * 32 + c]
           + y2r[a] * m3[a * 32 + c]
           + y3r[a] * m4[a * 32 + c];
    }
    out[g] = s;
}

extern "C" void kernel_launch(void* const* d_in, const int* in_sizes, int n_in,
                              void* d_out, int out_size, void* d_ws, size_t ws_size,
                              hipStream_t stream) {
    const float* x  = (const float*)d_in[0];   // 8192 x 32
    const float* ws = (const float*)d_in[1];   // 8192 x 8192
    const float* wp = (const float*)d_in[2];   // 32 x 32
    const float* ts = (const float*)d_in[3];   // 4 x 32 x 32
    const float* td = (const float*)d_in[4];   // 4 x 32 x 32
    float* out = (float*)d_out;

    char* w = (char*)d_ws;

    // ---- cooperative layout (~30 MB) ----
    float* Yp = (float*)w;                                  // 3 x 8 MB partial buffers
    float* xp = Yp + 3 * 2097152;
    float* y1 = xp + 262144;
    float* y2 = y1 + 262144;
    float* y3 = y2 + 262144;
    unsigned short* Vb0 = (unsigned short*)(y3 + 262144);   // 3 x 512 KB frag-ordered B
    unsigned short* Vb1 = Vb0 + 262144;
    unsigned short* Vb2 = Vb1 + 262144;
    float* Gpart = (float*)(Vb2 + 262144);                  // 64 x 1024
    float* Cx  = Gpart + 65536;
    float* Cxp = Cx + 1024;

    void* args[] = {(void*)&x, (void*)&ws, (void*)&wp, (void*)&ts, (void*)&td,
                    (void*)&out, (void*)&xp, (void*)&y1, (void*)&y2, (void*)&y3,
                    (void*)&Vb0, (void*)&Vb1, (void*)&Vb2, (void*)&Yp,
                    (void*)&Gpart, (void*)&Cx, (void*)&Cxp};
    hipError_t err = hipLaunchCooperativeKernel((void*)k_all, dim3(1024), dim3(256),
                                                args, 0, stream);
    if (err == hipSuccess) return;

    // ---- fallback: R6 multi-kernel path (own layout, nothing written yet) ----
    unsigned short* wsb = (unsigned short*)w;               // 128 MB frag-ordered bf16
    float* Ppart = (float*)(w + 134217728);                 // NSPLIT x 8192 x 32
    float* fxp = Ppart + (size_t)NSPLIT * 262144;
    float* fy1 = fxp + 262144;
    float* fy2 = fy1 + 262144;
    float* fy3 = fy2 + 262144;
    unsigned short* fVb = (unsigned short*)(fy3 + 262144);
    float* fGpart = (float*)(fVb + 262144);
    float* fCx  = fGpart + 32768;
    float* fCxp = fCx + 1024;

    dim3 gg(128, NSPLIT);
    k_prep<<<32, 256, 0, stream>>>(x, wp, fxp, fGpart, fVb);
    k_coef<<<1, 1024, 0, stream>>>(fGpart, wp, ts, td, fCx, fCxp);
    k_gemm1<<<gg, 256, 0, stream>>>(ws, wsb, fVb, Ppart);
    k_trans<<<32, 256, 0, stream>>>(Ppart, x, 1.0f, 0.0f, fy1, fVb);
    k_gemm2<<<gg, 256, 0, stream>>>(wsb, fVb, Ppart);
    k_trans<<<32, 256, 0, stream>>>(Ppart, x, 2.0f, -1.0f, fy2, fVb);
    k_gemm2<<<gg, 256, 0, stream>>>(wsb, fVb, Ppart);
    k_trans<<<32, 256, 0, stream>>>(Ppart, fy1, 2.0f, -1.0f, fy3, fVb);
    k_final<<<1024, 256, 0, stream>>>(x, fxp, fy1, fy2, fy3, fCx, fCxp, ts, out);
}

// Round 4
// 456.170 us; speedup vs baseline: 2.9720x; 2.9720x over previous
//
#include <hip/hip_runtime.h>

// GlobalSLC: out = out_s + out_d
//   static : y1 = ws@x; y2 = 2ws@y1 - x; y3 = 2ws@y2 - y1
//   dynamic: collapses to 32x32 algebra (G = x^T x, W = G wp, H1 = W G, H2 = 2 W H1 - G)
//   out = x@(2ts0-td2) + xp@(G td1 + 2 H1 td2 + (2H2-G) td3) + y1@ts1 + y2@ts2 + y3@ts3
//
// R8b: resubmit of the R8 4-launch full-K scheme (R3 bench was an infra flake).
// 1024-thread blocks own 32 complete rows (16 waves = 2 row-groups x 8 K-slices
// of 1024, LDS-reduced in-block). Split-K partials (Ypart), k_trans, k_coef,
// k_final all eliminated: each gemm block applies alpha/beta, emits Vb, and
// pass 3 computes `out` directly. ws fp32 is read once (nt, fragment-order,
// full-line use); bf16 wsb is written once with regular stores so passes 2/3
// read it from L2/L3. Coef algebra runs as block #256 of the pass-1 launch.

typedef __attribute__((ext_vector_type(8))) short short8;
typedef __attribute__((ext_vector_type(4))) float floatx4;

__device__ inline unsigned short f2bf(float f) {
    union { float f; unsigned u; } v; v.f = f;
    unsigned r = v.u + 0x7FFFu + ((v.u >> 16) & 1u);   // RNE
    return (unsigned short)(r >> 16);
}

__device__ inline floatx4 ntload4(const float* p) {
    return __builtin_nontemporal_load((const floatx4*)p);
}

// ---------- prep: xp = x@wp, Gram partials, Vb = fragment-ordered bf16(x) ----------
// (verbatim from the verified R6 kernel)
__global__ __launch_bounds__(256) void k_prep(const float* __restrict__ x,
                                              const float* __restrict__ wp,
                                              float* __restrict__ xp,
                                              float* __restrict__ Gpart,
                                              unsigned short* __restrict__ Vb) {
    __shared__ float sx[8192];
    __shared__ float swp[1024];
    __shared__ unsigned short st[32][264];
    const int t = threadIdx.x;
    const int n0 = blockIdx.x * 256;
    const floatx4* x4 = (const floatx4*)(x + (size_t)n0 * 32);
    floatx4* sx4 = (floatx4*)sx;
#pragma unroll
    for (int i = 0; i < 8; ++i) sx4[i * 256 + t] = x4[i * 256 + t];
    for (int i = t; i < 1024; i += 256) swp[i] = wp[i];
    __syncthreads();
    float row[32];
#pragma unroll
    for (int a = 0; a < 32; ++a) row[a] = sx[t * 32 + a];
    float* xpr = xp + (size_t)(n0 + t) * 32;
#pragma unroll
    for (int c = 0; c < 32; ++c) {
        float s = 0.f;
#pragma unroll
        for (int a = 0; a < 32; ++a) s += row[a] * swp[a * 32 + c];
        xpr[c] = s;
        st[c][t] = f2bf(row[c]);
    }
    const int a = t >> 3;
    const int b = 4 * (t & 7);
    float g0 = 0.f, g1 = 0.f, g2 = 0.f, g3 = 0.f;
    for (int i = 0; i < 256; ++i) {
        float va = sx[i * 32 + a];
        floatx4 vb = *(floatx4*)&sx[i * 32 + b];
        g0 += va * vb.x; g1 += va * vb.y; g2 += va * vb.z; g3 += va * vb.w;
    }
    floatx4 g = {g0, g1, g2, g3};
    *(floatx4*)&Gpart[(size_t)blockIdx.x * 1024 + (size_t)(a * 32 + b)] = g;
    __syncthreads();
    const int lane = t & 63, wv = t >> 6;
    const int l15 = lane & 15, l4 = lane >> 4;
    short8* Vb8 = (short8*)Vb;
#pragma unroll
    for (int q = 0; q < 4; ++q) {
        int idx = wv * 4 + q;
        int c8 = idx >> 1, h = idx & 1;
        short8 v = *(const short8*)&st[h * 16 + l15][c8 * 32 + l4 * 8];
        Vb8[((size_t)(n0 / 32 + c8) * 2 + h) * 64 + lane] = v;
    }
}

// ---------- fused Chebyshev pass ----------
// MODE 1: A = ws fp32 (nt, fragment-order read), writes wsb; emits y1,Vb1; block 256 = coef
// MODE 2: A = wsb bf16; emits y2,Vb2
// MODE 3: A = wsb bf16; computes out directly (no y/Vb writes)
struct __align__(16) ChebSM {
    union {
        float red[16 * 512];                                        // 32 KB
        struct { float G[1024], W[1024], H1[1024], H2[1024]; } coef; // 16 KB
        float fin[5 * 1024];                                        // 20 KB (MODE 3)
    };
    union {
        unsigned short st16[32][48];                                // 3 KB (MODE 1,2)
        struct { float y3s[32][33], xs[32][33], xps[32][33],
                       y1s[32][33], y2s[32][33]; } f;               // 20.6 KB (MODE 3)
    };
};

template <int MODE>
__global__ __launch_bounds__(1024, 4) void k_cheb(
    const float* __restrict__ wsf, unsigned short* __restrict__ wsb,
    const unsigned short* __restrict__ VbIn,
    const float* __restrict__ prev, float alpha, float beta,
    float* __restrict__ yout, unsigned short* __restrict__ VbOut,
    const float* __restrict__ Gpart, const float* __restrict__ wp,
    const float* __restrict__ ts, const float* __restrict__ td,
    float* __restrict__ Cx, float* __restrict__ Cxp,
    const float* __restrict__ x, const float* __restrict__ xp,
    const float* __restrict__ y1, const float* __restrict__ y2,
    float* __restrict__ out)
{
    __shared__ ChebSM sm;
    const int t = threadIdx.x;
    const int bid = blockIdx.x;

    if (MODE == 1 && bid == 256) {
        // ---- 32x32 coefficient algebra (1024 threads, one element each) ----
        const int a = t >> 5, b = t & 31;
        float g = 0.f;
        for (int p = 0; p < 32; ++p) g += Gpart[p * 1024 + t];
        sm.coef.G[t] = g;
        __syncthreads();
        float s = 0.f;
        for (int c = 0; c < 32; ++c) s += sm.coef.G[a * 32 + c] * wp[c * 32 + b];
        sm.coef.W[t] = s;
        __syncthreads();
        s = 0.f;
        for (int c = 0; c < 32; ++c) s += sm.coef.W[a * 32 + c] * sm.coef.G[c * 32 + b];
        sm.coef.H1[t] = s;
        __syncthreads();
        s = 0.f;
        for (int c = 0; c < 32; ++c) s += sm.coef.W[a * 32 + c] * sm.coef.H1[c * 32 + b];
        sm.coef.H2[t] = 2.f * s - sm.coef.G[t];
        __syncthreads();
        s = 0.f;
        for (int c = 0; c < 32; ++c)
            s += sm.coef.G[a * 32 + c] * td[1024 + c * 32 + b]
               + 2.f * sm.coef.H1[a * 32 + c] * td[2048 + c * 32 + b]
               + (2.f * sm.coef.H2[a * 32 + c] - sm.coef.G[a * 32 + c]) * td[3072 + c * 32 + b];
        Cxp[t] = s;
        Cx[t] = 2.f * ts[t] - td[2048 + t];
        return;
    }

    const int lane = t & 63, wv = t >> 6;
    const int l15 = lane & 15, l4 = lane >> 4;
    const int rg = wv >> 3, ks = wv & 7;       // row-group (2) x K-slice (8)
    const int n0 = bid * 32;

    floatx4 acc0 = {0.f, 0.f, 0.f, 0.f};
    floatx4 acc1 = {0.f, 0.f, 0.f, 0.f};
    const short8* Vb8 = (const short8*)VbIn;

    if (MODE == 1) {
        // fragment-order direct read of ws fp32: row = n0+rg*16+l15, k = ks*1024+c*32+l4*8
        const float* arow = wsf + (size_t)(n0 + rg * 16 + l15) * 8192 + ks * 1024 + l4 * 8;
        short8* wout = (short8*)wsb + (((size_t)(bid * 2 + rg) * 8 + ks) * 32) * 64 + lane;
#pragma unroll 4
        for (int c = 0; c < 32; ++c) {
            floatx4 f0 = ntload4(arow + c * 32);
            floatx4 f1 = ntload4(arow + c * 32 + 4);
            short8 av;
            av[0] = (short)f2bf(f0.x); av[1] = (short)f2bf(f0.y);
            av[2] = (short)f2bf(f0.z); av[3] = (short)f2bf(f0.w);
            av[4] = (short)f2bf(f1.x); av[5] = (short)f2bf(f1.y);
            av[6] = (short)f2bf(f1.z); av[7] = (short)f2bf(f1.w);
            const int gkc = ks * 32 + c;
            short8 b0 = Vb8[((size_t)gkc * 2 + 0) * 64 + lane];
            short8 b1 = Vb8[((size_t)gkc * 2 + 1) * 64 + lane];
            wout[(size_t)c * 64] = av;
            acc0 = __builtin_amdgcn_mfma_f32_16x16x32_bf16(av, b0, acc0, 0, 0, 0);
            acc1 = __builtin_amdgcn_mfma_f32_16x16x32_bf16(av, b1, acc1, 0, 0, 0);
        }
    } else {
        const short8* win = (const short8*)wsb + (((size_t)(bid * 2 + rg) * 8 + ks) * 32) * 64 + lane;
#pragma unroll 8
        for (int c = 0; c < 32; ++c) {
            short8 av = win[(size_t)c * 64];
            const int gkc = ks * 32 + c;
            short8 b0 = Vb8[((size_t)gkc * 2 + 0) * 64 + lane];
            short8 b1 = Vb8[((size_t)gkc * 2 + 1) * 64 + lane];
            acc0 = __builtin_amdgcn_mfma_f32_16x16x32_bf16(av, b0, acc0, 0, 0, 0);
            acc1 = __builtin_amdgcn_mfma_f32_16x16x32_bf16(av, b1, acc1, 0, 0, 0);
        }
    }

    // ---- write per-wave acc tiles to LDS ----
    {
        const int base = (rg * 8 + ks) * 512;
#pragma unroll
        for (int r = 0; r < 4; ++r) {
            sm.red[base + (l4 * 4 + r) * 32 + l15]      = acc0[r];
            sm.red[base + (l4 * 4 + r) * 32 + 16 + l15] = acc1[r];
        }
    }
    __syncthreads();

    // ---- reduce over the 8 K-slices; alpha/beta ----
    const int rr = t >> 5, cc = t & 31;          // row in tile, col
    const int rrg = rr >> 4, rrl = rr & 15;
    float s = 0.f;
#pragma unroll
    for (int k = 0; k < 8; ++k) s += sm.red[(rrg * 8 + k) * 512 + rrl * 32 + cc];
    const float pv = prev[(size_t)(n0 + rr) * 32 + cc];
    const float v = alpha * s + beta * pv;

    if (MODE != 3) {
        yout[(size_t)(n0 + rr) * 32 + cc] = v;
        sm.st16[cc][rr] = f2bf(v);
        __syncthreads();
        if (t < 128) {
            const int h = t >> 6, ln = t & 63;
            const int hl15 = ln & 15, hl4 = ln >> 4;
            short8 v8 = *(const short8*)&sm.st16[h * 16 + hl15][hl4 * 8];
            ((short8*)VbOut)[((size_t)bid * 2 + h) * 64 + ln] = v8;
        }
    } else {
        // ---- final: out = x@Cx + xp@Cxp + y1@ts1 + y2@ts2 + y3@ts3 ----
        sm.f.y3s[rr][cc] = v;
        __syncthreads();                          // red fully consumed
        sm.fin[t]        = Cx[t];
        sm.fin[1024 + t] = Cxp[t];
        sm.fin[2048 + t] = ts[1024 + t];
        sm.fin[3072 + t] = ts[2048 + t];
        sm.fin[4096 + t] = ts[3072 + t];
        const size_t gidx = (size_t)(n0 + rr) * 32 + cc;
        sm.f.xs[rr][cc]  = x[gidx];
        sm.f.xps[rr][cc] = xp[gidx];
        sm.f.y1s[rr][cc] = y1[gidx];
        sm.f.y2s[rr][cc] = y2[gidx];
        __syncthreads();
        float o = 0.f;
#pragma unroll
        for (int a = 0; a < 32; ++a) {
            o += sm.f.xs[rr][a]  * sm.fin[a * 32 + cc]
               + sm.f.xps[rr][a] * sm.fin[1024 + a * 32 + cc]
               + sm.f.y1s[rr][a] * sm.fin[2048 + a * 32 + cc]
               + sm.f.y2s[rr][a] * sm.fin[3072 + a * 32 + cc]
               + sm.f.y3s[rr][a] * sm.fin[4096 + a * 32 + cc];
        }
        out[gidx] = o;
    }
}

extern "C" void kernel_launch(void* const* d_in, const int* in_sizes, int n_in,
                              void* d_out, int out_size, void* d_ws, size_t ws_size,
                              hipStream_t stream) {
    const float* x  = (const float*)d_in[0];   // 8192 x 32
    const float* ws = (const float*)d_in[1];   // 8192 x 8192
    const float* wp = (const float*)d_in[2];   // 32 x 32
    const float* ts = (const float*)d_in[3];   // 4 x 32 x 32
    const float* td = (const float*)d_in[4];   // 4 x 32 x 32
    float* out = (float*)d_out;

    char* w = (char*)d_ws;
    unsigned short* wsb = (unsigned short*)w;              // 128 MB frag-ordered bf16
    float* xp  = (float*)(w + 134217728);                  // 8192 x 32
    float* y1  = xp + 262144;
    float* y2  = y1 + 262144;
    unsigned short* Vb0 = (unsigned short*)(y2 + 262144);  // 3 x 512 KB frag-ordered B
    unsigned short* Vb1 = Vb0 + 262144;
    unsigned short* Vb2 = Vb1 + 262144;
    float* Gpart = (float*)(Vb2 + 262144);                 // 32 x 1024
    float* Cx  = Gpart + 32768;
    float* Cxp = Cx + 1024;

    k_prep<<<32, 256, 0, stream>>>(x, wp, xp, Gpart, Vb0);

    // pass 1: y1 = ws @ x  (+ wsb emit, + coef block #256)
    k_cheb<1><<<257, 1024, 0, stream>>>(ws, wsb, Vb0, x, 1.0f, 0.0f, y1, Vb1,
                                        Gpart, wp, ts, td, Cx, Cxp,
                                        x, xp, y1, y2, out);
    // pass 2: y2 = 2 ws @ y1 - x
    k_cheb<2><<<256, 1024, 0, stream>>>(nullptr, wsb, Vb1, x, 2.0f, -1.0f, y2, Vb2,
                                        nullptr, nullptr, nullptr, nullptr, nullptr, nullptr,
                                        nullptr, nullptr, nullptr, nullptr, nullptr);
    // pass 3: y3 = 2 ws @ y2 - y1, fused final -> out
    k_cheb<3><<<256, 1024, 0, stream>>>(nullptr, wsb, Vb2, y1, 2.0f, -1.0f, nullptr, nullptr,
                                        nullptr, nullptr, ts, nullptr, Cx, Cxp,
                                        x, xp, y1, y2, out);
}